// Round 4
// baseline (79.126 us; speedup 1.0000x reference)
//
#include <hip/hip_runtime.h>

#define IMG_H 1080
#define IMG_W 1920
#define CH 3
#define TH 12            // rows per strip; 1080 = 90 * 12

__global__ __launch_bounds__(128, 4)
void dssim_l1_kernel(const float* __restrict__ pred,
                     const float* __restrict__ gt,
                     float* __restrict__ out) {
    constexpr float K1 = 81.0f * 0.0001f;        // 81*C1
    constexpr float K2 = 81.0f * 0.0009f;        // 81*C2
    constexpr float A3 = 0.85f / 3.0f;
    constexpr float B3 = 0.15f / 3.0f;

    const int tx    = threadIdx.x;                        // 0..63
    const int col   = blockIdx.x * 64 + tx;
    const int strip = blockIdx.y * 2 + threadIdx.y;       // 0..89
    const int h0    = strip * TH;
    const int b     = blockIdx.z;

    // reflect-clamped neighbor columns
    const int cm1 = abs(col - 1);                              // col 0 -> 1
    const int cp1 = min(col + 1, 2 * (IMG_W - 1) - col - 1);   // col 1919 -> 1918

    const size_t img = (size_t)IMG_H * IMG_W;
    const float* __restrict__ xb = pred + (size_t)b * CH * img;
    const float* __restrict__ yb = gt   + (size_t)b * CH * img;

    // rolling 3-row window stats per channel (static indices only)
    float hx[CH][3], hy[CH][3], hxx[CH][3], hyy[CH][3], hxy[CH][3];
    // double-buffered raw row values: [c][0..2]=x(cm1,col,cp1), [3..5]=y
    float pA[CH][6], pB[CH][6];

    // issue 6 loads of global row gr into buffer P
#define ISSUE(P, gr)                                                        \
    {                                                                       \
        const size_t rb_ = (size_t)(gr) * IMG_W;                            \
        _Pragma("unroll")                                                   \
        for (int c = 0; c < CH; ++c) {                                      \
            const size_t cb_ = (size_t)c * img + rb_;                       \
            P[c][0] = xb[cb_ + cm1];                                        \
            P[c][1] = xb[cb_ + col];                                        \
            P[c][2] = xb[cb_ + cp1];                                        \
            P[c][3] = yb[cb_ + cm1];                                        \
            P[c][4] = yb[cb_ + col];                                        \
            P[c][5] = yb[cb_ + cp1];                                        \
        }                                                                   \
    }

    // turn raw buffer P into horizontal 3-tap stats in slot S
#define CONSUME(P, S)                                                       \
    {                                                                       \
        _Pragma("unroll")                                                   \
        for (int c = 0; c < CH; ++c) {                                      \
            float x0 = P[c][0], x1 = P[c][1], x2 = P[c][2];                 \
            float y0 = P[c][3], y1 = P[c][4], y2 = P[c][5];                 \
            hx[c][S]  = x0 + x1 + x2;                                       \
            hy[c][S]  = y0 + y1 + y2;                                       \
            hxx[c][S] = x0 * x0 + x1 * x1 + x2 * x2;                        \
            hyy[c][S] = y0 * y0 + y1 * y1 + y2 * y2;                        \
            hxy[c][S] = x0 * y0 + x1 * y1 + x2 * y2;                        \
        }                                                                   \
    }

    // ---- warmup ----
    {
        const int gm = (h0 == 0) ? 1 : h0 - 1;   // reflect(-1) = 1
        ISSUE(pA, gm);       // row h0-1
        CONSUME(pA, 0);
        ISSUE(pB, h0);       // row h0 (raw kept for iter-0 L1)
        CONSUME(pB, 1);
        ISSUE(pA, h0 + 1);   // raw only; consumed at iter 0
    }

    float* op = out + ((size_t)b * IMG_H + h0) * IMG_W + col;

    // iter k: L1 from POUT (row k raw), issue row k+2 into POUT,
    //         consume PIN (row k+1) into slot S, SSIM for output row k.
#define STEP(KK, S, PIN, POUT)                                              \
    {                                                                       \
        const int r_ = kb + (KK) + 2;                                       \
        const int gr_ = min(r_, 2 * (IMG_H - 1) - r_);                      \
        float res = 0.0f;                                                   \
        float l1v[CH];                                                      \
        _Pragma("unroll")                                                   \
        for (int c = 0; c < CH; ++c)                                        \
            l1v[c] = fabsf(POUT[c][1] - POUT[c][4]);                        \
        ISSUE(POUT, gr_);                                                   \
        CONSUME(PIN, S);                                                    \
        _Pragma("unroll")                                                   \
        for (int c = 0; c < CH; ++c) {                                      \
            float ax  = hx[c][0]  + hx[c][1]  + hx[c][2];                   \
            float ay  = hy[c][0]  + hy[c][1]  + hy[c][2];                   \
            float axx = hxx[c][0] + hxx[c][1] + hxx[c][2];                  \
            float ayy = hyy[c][0] + hyy[c][1] + hyy[c][2];                  \
            float axy = hxy[c][0] + hxy[c][1] + hxy[c][2];                  \
            float u = ax * ay;                                              \
            float v = fmaf(ay, ay, ax * ax);                                \
            float w = axx + ayy;                                            \
            float num1 = fmaf(2.0f, u, K1);                                 \
            float num2 = fmaf(18.0f, axy, fmaf(-2.0f, u, K2));              \
            float den1 = v + K1;                                            \
            float den2 = fmaf(9.0f, w, K2) - v;                             \
            float n = num1 * num2;                                          \
            float d = den1 * den2;                                          \
            float s = fmaf(-0.5f, n * __builtin_amdgcn_rcpf(d), 0.5f);      \
            s = fminf(fmaxf(s, 0.0f), 1.0f);                                \
            res = fmaf(A3, s, fmaf(B3, l1v[c], res));                       \
        }                                                                   \
        *op = res;                                                          \
        op += IMG_W;                                                        \
    }

    for (int kc = 0; kc < TH / 6; ++kc) {
        const int kb = h0 + kc * 6;
        STEP(0, 2, pA, pB)
        STEP(1, 0, pB, pA)
        STEP(2, 1, pA, pB)
        STEP(3, 2, pB, pA)
        STEP(4, 0, pA, pB)
        STEP(5, 1, pB, pA)
    }
#undef STEP
#undef CONSUME
#undef ISSUE
}

extern "C" void kernel_launch(void* const* d_in, const int* in_sizes, int n_in,
                              void* d_out, int out_size, void* d_ws, size_t ws_size,
                              hipStream_t stream) {
    const float* pred = (const float*)d_in[0];
    const float* gt   = (const float*)d_in[1];
    float* out = (float*)d_out;

    dim3 block(64, 2, 1);
    dim3 grid(IMG_W / 64, (IMG_H / TH) / 2, 4);   // 30 x 45 x 4
    dssim_l1_kernel<<<grid, block, 0, stream>>>(pred, gt, out);
}